// Round 16
// baseline (574.171 us; speedup 1.0000x reference)
//
#include <hip/hip_runtime.h>
#include <math.h>
#include <stdint.h>

#define CH 256

typedef _Float16 half8 __attribute__((ext_vector_type(8)));
typedef _Float16 half4 __attribute__((ext_vector_type(4)));
typedef _Float16 half2v __attribute__((ext_vector_type(2)));
typedef float f32x4 __attribute__((ext_vector_type(4)));

__device__ __forceinline__ float gelu_exact(float v) {
    return 0.5f * v * (1.0f + erff(v * 0.70710678118654752f));
}

// acc += hi + lo of a packed (hi,lo) u32, one VALU op via v_dot2_f32_f16
__device__ __forceinline__ float acc_pk(uint32_t u, float acc) {
    half2v h = __builtin_bit_cast(half2v, u);
#if __has_builtin(__builtin_amdgcn_fdot2)
    half2v ones = {(_Float16)1.0f, (_Float16)1.0f};
    return __builtin_amdgcn_fdot2(h, ones, acc, false);
#else
    return acc + (float)h.x + (float)h.y;
#endif
}

// ---- W1/W2 pre-split into k-tiled transposed layout: WT[mat][kt][n][32] ----
__global__ void wsplit_kernel(const float* __restrict__ W1, const float* __restrict__ W2,
                              _Float16* __restrict__ WThi, _Float16* __restrict__ WTlo) {
    int idx = blockIdx.x * blockDim.x + threadIdx.x;  // 65536 threads
    int n   = idx & 255;
    int kg  = (idx >> 8) & 31;     // k-group of 8
    int mat = idx >> 13;
    const float* W = (mat < 4) ? (W1 + (size_t)mat * 65536)
                               : (W2 + (size_t)(mat - 4) * 65536);
    _Float16 hi[8], lo[8];
#pragma unroll
    for (int j = 0; j < 8; j++) {
        float v = W[(size_t)(kg * 8 + j) * CH + n];
        _Float16 h = (_Float16)v;
        hi[j] = h;
        lo[j] = (_Float16)(v - (float)h);
    }
    size_t off = (size_t)mat * 65536 + ((size_t)(kg >> 2) * 256 + n) * 32 + (kg & 3) * 8;
    *(half8*)(WThi + off) = *(half8*)&hi[0];
    *(half8*)(WTlo + off) = *(half8*)&lo[0];
}

// ---- W_embed pre-split tiled: [4][256][32] (K padded 118 -> 128) ----
__global__ void wesplit_kernel(const float* __restrict__ We,
                               _Float16* __restrict__ WeTh, _Float16* __restrict__ WeTl) {
    int idx = blockIdx.x * blockDim.x + threadIdx.x;  // 4096 threads
    if (idx >= 4096) return;
    int n  = idx >> 4;
    int k8 = (idx & 15) * 8;
    _Float16 hi[8], lo[8];
#pragma unroll
    for (int j = 0; j < 8; j++) {
        int k = k8 + j;
        float v = (k < 118) ? We[(size_t)k * CH + n] : 0.f;
        _Float16 h = (_Float16)v;
        hi[j] = h;
        lo[j] = (_Float16)(v - (float)h);
    }
    size_t off = ((size_t)(k8 >> 5) * 256 + n) * 32 + (k8 & 31);
    *(half8*)(WeTh + off) = *(half8*)&hi[0];
    *(half8*)(WeTl + off) = *(half8*)&lo[0];
}

// ---- x pre-split tiled: [4][Mpad][32] ----
__global__ void xsplit_kernel(const float* __restrict__ x,
                              _Float16* __restrict__ xh, _Float16* __restrict__ xl,
                              int N, int Mpad) {
    int idx = blockIdx.x * blockDim.x + threadIdx.x;
    int n  = idx >> 4;
    int c8 = (idx & 15) * 8;
    if (n >= N) return;
    _Float16 hi[8], lo[8];
#pragma unroll
    for (int j = 0; j < 8; j++) {
        int c = c8 + j;
        float v = (c < 118) ? x[(size_t)n * 118 + c] : 0.f;
        _Float16 h = (_Float16)v;
        hi[j] = h;
        lo[j] = (_Float16)(v - (float)h);
    }
    size_t off = ((size_t)(c8 >> 5) * Mpad + n) * 32 + (c8 & 31);
    *(half8*)(xh + off) = *(half8*)&hi[0];
    *(half8*)(xl + off) = *(half8*)&lo[0];
}

// ---- fp16-split 3-pass MFMA GEMM: B-resident-in-LDS, A direct-to-register ----
// B (64-col panel, hi+lo) staged into LDS ONCE; K-loop has ZERO barriers:
// {8x 1KB-coalesced global A-frag loads || 4 ds_reads || 24 MFMA} per kt,
// freely software-pipelined by the compiler. XCD-swizzled grid keeps A L2-hot.
// B LDS stride 264 halves (528B): 16B-aligned stores, <=2-way frag-read banks.
template<int KT, bool DOGELU, bool TILED>
__global__ __launch_bounds__(256, 2) void mgemm_kernel(
    const _Float16* __restrict__ Ah_g, const _Float16* __restrict__ Al_g,
    const _Float16* __restrict__ Bh_g, const _Float16* __restrict__ Bl_g,
    const float* __restrict__ bias,
    _Float16* __restrict__ Oh, _Float16* __restrict__ Ol,
    int Mpad, int MC)
{
    const int BST = KT * 32 + 8;                 // padded col stride (halves)
    __shared__ _Float16 Bh_s[64][KT * 32 + 8];
    __shared__ _Float16 Bl_s[64][KT * 32 + 8];

    int b    = blockIdx.x;
    int xcd  = b & 7;
    int slot = b >> 3;
    int mt   = xcd * MC + (slot >> 2);
    int nt   = slot & 3;
    if (mt * 128 >= Mpad) return;
    int m0 = mt * 128;
    int n0 = nt * 64;

    int tid  = threadIdx.x;
    int lane = tid & 63;
    int wave = tid >> 6;
    int wr = wave >> 1;
    int wc = wave & 1;

    // ---- stage B panel once (hi+lo) ----
    {
        const int CH8 = KT * 4;                  // half8 chunks per col
        for (int i = tid; i < 64 * CH8; i += 256) {
            int c   = i / CH8;
            int kc8 = (i % CH8) * 8;
            int kt_ = kc8 >> 5, kw = kc8 & 31;
            size_t src = ((size_t)kt_ * 256 + (n0 + c)) * 32 + kw;
            *(half8*)&Bh_s[c][kc8] = *(const half8*)(Bh_g + src);
            *(half8*)&Bl_s[c][kc8] = *(const half8*)(Bl_g + src);
        }
    }
    __syncthreads();

    f32x4 acc[4][2];
#pragma unroll
    for (int i = 0; i < 4; i++)
#pragma unroll
        for (int j = 0; j < 2; j++) acc[i][j] = (f32x4){0.f, 0.f, 0.f, 0.f};

    int frow = lane & 15;
    int fk   = (lane >> 4) * 8;

    // ---- barrier-free K-loop ----
#pragma unroll
    for (int kt = 0; kt < KT; kt++) {
        half8 ah[4], al[4], bh[2], bl[2];
#pragma unroll
        for (int rf = 0; rf < 4; rf++) {
            size_t ro = ((size_t)kt * Mpad + (m0 + wr * 64 + rf * 16 + frow)) * 32 + fk;
            ah[rf] = *(const half8*)(Ah_g + ro);
            al[rf] = *(const half8*)(Al_g + ro);
        }
#pragma unroll
        for (int cf = 0; cf < 2; cf++) {
            int c = wc * 32 + cf * 16 + frow;
            bh[cf] = *(const half8*)&Bh_s[c][kt * 32 + fk];
            bl[cf] = *(const half8*)&Bl_s[c][kt * 32 + fk];
        }
#pragma unroll
        for (int rf = 0; rf < 4; rf++)
#pragma unroll
            for (int cf = 0; cf < 2; cf++) {
                acc[rf][cf] = __builtin_amdgcn_mfma_f32_16x16x32_f16(ah[rf], bh[cf], acc[rf][cf], 0, 0, 0);
                acc[rf][cf] = __builtin_amdgcn_mfma_f32_16x16x32_f16(ah[rf], bl[cf], acc[rf][cf], 0, 0, 0);
                acc[rf][cf] = __builtin_amdgcn_mfma_f32_16x16x32_f16(al[rf], bh[cf], acc[rf][cf], 0, 0, 0);
            }
    }
    __syncthreads();   // B no longer needed; LDS reused as Obuf

    // ---- epilogue: pack hi/lo u32 -> LDS -> coalesced stores ----
    uint32_t (*Obuf)[68] = (uint32_t(*)[68])&Bh_s[0][0];    // 17408B <= B region
    int ccol = lane & 15;
    int crow = (lane >> 4) * 4;
    float bb[2];
    bb[0] = bias[n0 + wc * 32 + ccol];
    bb[1] = bias[n0 + wc * 32 + 16 + ccol];
#pragma unroll
    for (int half = 0; half < 2; half++) {
        if (wr == half) {
#pragma unroll
            for (int cf = 0; cf < 2; cf++)
#pragma unroll
                for (int rf = 0; rf < 4; rf++)
#pragma unroll
                    for (int q = 0; q < 4; q++) {
                        float v = acc[rf][cf][q] + bb[cf];
                        float g = DOGELU ? gelu_exact(v) : v;
                        _Float16 hi = (_Float16)g;
                        _Float16 lo = (_Float16)(g - (float)hi);
                        uint32_t u = (uint32_t)__builtin_bit_cast(uint16_t, hi)
                                   | ((uint32_t)__builtin_bit_cast(uint16_t, lo) << 16);
                        Obuf[rf * 16 + crow + q][wc * 32 + cf * 16 + ccol] = u;
                    }
        }
        __syncthreads();
#pragma unroll
        for (int i = 0; i < 8; i++) {
            int idx = i * 512 + tid * 2;
            int row = idx >> 6;
            int c   = idx & 63;
            uint32_t u0 = Obuf[row][c];
            uint32_t u1 = Obuf[row][c + 1];
            int grow = m0 + half * 64 + row;
            int gcol = n0 + c;
            if (TILED) {
                uint32_t hi2 = (u0 & 0xffffu) | (u1 << 16);
                uint32_t lo2 = (u0 >> 16) | (u1 & 0xffff0000u);
                size_t off = ((size_t)(gcol >> 5) * Mpad + grow) * 32 + (gcol & 31);
                *(uint32_t*)(Oh + off) = hi2;
                *(uint32_t*)(Ol + off) = lo2;
            } else {
                uint2 pk; pk.x = u0; pk.y = u1;
                *(uint2*)((uint32_t*)Oh + (size_t)grow * CH + gcol) = pk;
            }
        }
        __syncthreads();
    }
}

// ---------------- CSR build ----------------
__global__ void zero_int_kernel(int* p, int n) {
    int i = blockIdx.x * blockDim.x + threadIdx.x;
    if (i < n) p[i] = 0;
}

__global__ void degree_kernel(const int* __restrict__ ei, int E, int* deg) {
    int e = blockIdx.x * blockDim.x + threadIdx.x;
    if (e < E) atomicAdd(&deg[ei[E + e]], 1);
}

__global__ void scan_part_kernel(const int* __restrict__ deg, int* bsum, int N) {
    int t = threadIdx.x;
    int base = blockIdx.x * 1024 + t * 4;
    int4 v = {0, 0, 0, 0};
    if (base + 3 < N) v = *(const int4*)(deg + base);
    else {
        if (base + 0 < N) v.x = deg[base + 0];
        if (base + 1 < N) v.y = deg[base + 1];
        if (base + 2 < N) v.z = deg[base + 2];
        if (base + 3 < N) v.w = deg[base + 3];
    }
    __shared__ int sh[256];
    sh[t] = v.x + v.y + v.z + v.w;
    __syncthreads();
    for (int off = 128; off; off >>= 1) {
        if (t < off) sh[t] += sh[t + off];
        __syncthreads();
    }
    if (t == 0) bsum[blockIdx.x] = sh[0];
}

__global__ void scan_top_kernel(const int* __restrict__ bsum, int* boff, int B) {
    __shared__ int sh[256];
    int t = threadIdx.x;
    int own = (t < B) ? bsum[t] : 0;
    sh[t] = own;
    __syncthreads();
    for (int off = 1; off < 256; off <<= 1) {
        int v = (t >= off) ? sh[t - off] : 0;
        __syncthreads();
        sh[t] += v;
        __syncthreads();
    }
    if (t < B) boff[t] = sh[t] - own;
}

__global__ void scan_final_kernel(const int* __restrict__ deg, const int* __restrict__ boff,
                                  int* row_ptr, int* fill_pos, float* inv, int N, int E) {
    int t = threadIdx.x;
    int base = blockIdx.x * 1024 + t * 4;
    int4 v = {0, 0, 0, 0};
    if (base + 3 < N) v = *(const int4*)(deg + base);
    else {
        if (base + 0 < N) v.x = deg[base + 0];
        if (base + 1 < N) v.y = deg[base + 1];
        if (base + 2 < N) v.z = deg[base + 2];
        if (base + 3 < N) v.w = deg[base + 3];
    }
    int own = v.x + v.y + v.z + v.w;
    __shared__ int sh[256];
    sh[t] = own;
    __syncthreads();
    for (int off = 1; off < 256; off <<= 1) {
        int s = (t >= off) ? sh[t - off] : 0;
        __syncthreads();
        sh[t] += s;
        __syncthreads();
    }
    int run = boff[blockIdx.x] + (sh[t] - own);
    int4 rp;
    rp.x = run;
    rp.y = run + v.x;
    rp.z = rp.y + v.y;
    rp.w = rp.z + v.z;
    if (base + 3 < N) {
        *(int4*)(row_ptr + base) = rp;
        *(int4*)(fill_pos + base) = rp;
        float4 iv;
        iv.x = 1.0f / fmaxf((float)v.x, 1.0f);
        iv.y = 1.0f / fmaxf((float)v.y, 1.0f);
        iv.z = 1.0f / fmaxf((float)v.z, 1.0f);
        iv.w = 1.0f / fmaxf((float)v.w, 1.0f);
        *(float4*)(inv + base) = iv;
    } else {
        int rr[4] = {rp.x, rp.y, rp.z, rp.w};
        int dd[4] = {v.x, v.y, v.z, v.w};
        for (int q = 0; q < 4; q++) {
            if (base + q < N) {
                row_ptr[base + q] = rr[q];
                fill_pos[base + q] = rr[q];
                inv[base + q] = 1.0f / fmaxf((float)dd[q], 1.0f);
            }
        }
    }
    if (blockIdx.x == 0 && t == 0) row_ptr[N] = E;
}

__global__ void fill_kernel(const int* __restrict__ ei, int E, int* fill_pos, int* colv) {
    int e = blockIdx.x * blockDim.x + threadIdx.x;
    if (e < E) {
        int p = atomicAdd(&fill_pos[ei[E + e]], 1);
        colv[p] = ei[e];
    }
}

// ---- aggregation (R14, best): XCD slice + uint2 loads + fdot2, 16 lanes/node ----
__global__ __launch_bounds__(256) void agg_kernel(
    const uint32_t* __restrict__ tpk,
    const int* __restrict__ row_ptr, const int* __restrict__ colv,
    const float* __restrict__ inv,
    _Float16* __restrict__ aggh, _Float16* __restrict__ aggl,
    int N, int Mpad)
{
    int b = blockIdx.x;
    int slice = b & 7;                          // 32-channel slice, pinned to XCD
    int n = (b >> 3) * 16 + (threadIdx.x >> 4); // one node per 16-lane group
    if (n >= N) return;
    int lane = threadIdx.x & 15;
    const uint32_t* base = tpk + slice * 32 + lane * 2;

    int s = row_ptr[n], e = row_ptr[n + 1];
    float e0 = 0.f, o0 = 0.f, e1 = 0.f, o1 = 0.f;   // 2 accum pairs (even/odd ch)
    int j = s;
    for (; j + 4 <= e; j += 4) {
        int c0 = colv[j], c1 = colv[j + 1], c2 = colv[j + 2], c3 = colv[j + 3];
        uint2 u0 = *(const uint2*)(base + (size_t)c0 * CH);
        uint2 u1 = *(const uint2*)(base + (size_t)c1 * CH);
        uint2 u2 = *(const uint2*)(base + (size_t)c2 * CH);
        uint2 u3 = *(const uint2*)(base + (size_t)c3 * CH);
        e0 = acc_pk(u0.x, e0); o0 = acc_pk(u0.y, o0);
        e1 = acc_pk(u1.x, e1); o1 = acc_pk(u1.y, o1);
        e0 = acc_pk(u2.x, e0); o0 = acc_pk(u2.y, o0);
        e1 = acc_pk(u3.x, e1); o1 = acc_pk(u3.y, o1);
    }
    for (; j < e; j++) {
        uint2 u = *(const uint2*)(base + (size_t)colv[j] * CH);
        e0 = acc_pk(u.x, e0); o0 = acc_pk(u.y, o0);
    }
    float sc = inv[n];
    float v0 = (e0 + e1) * sc;
    float v1 = (o0 + o1) * sc;
    _Float16 h0 = (_Float16)v0, h1 = (_Float16)v1;
    half2v oh = {h0, h1};
    half2v ol = {(_Float16)(v0 - (float)h0), (_Float16)(v1 - (float)h1)};
    size_t ooff = ((size_t)slice * Mpad + n) * 32 + lane * 2;  // tiled [kt][Mpad][32]
    *(half2v*)(aggh + ooff) = oh;
    *(half2v*)(aggl + ooff) = ol;
}

__global__ void mean_kernel(const _Float16* __restrict__ hh, const _Float16* __restrict__ hl,
                            float* __restrict__ out, int N, int Mpad) {
    int n = blockIdx.x * 4 + (threadIdx.x >> 6);
    if (n >= N) return;
    int lane = threadIdx.x & 63;
    size_t off = ((size_t)(lane >> 3) * Mpad + n) * 32 + ((lane * 4) & 31);
    half4 vh = *(const half4*)(hh + off);
    half4 vl = *(const half4*)(hl + off);
    float s = 0.f;
#pragma unroll
    for (int q = 0; q < 4; q++) s += (float)vh[q] + (float)vl[q];
#pragma unroll
    for (int off2 = 32; off2; off2 >>= 1) s += __shfl_down(s, off2, 64);
    if (lane == 0) out[n] = s * (1.0f / 256.0f);
}

extern "C" void kernel_launch(void* const* d_in, const int* in_sizes, int n_in,
                              void* d_out, int out_size, void* d_ws, size_t ws_size,
                              hipStream_t stream) {
    const float* x       = (const float*)d_in[0];
    const int*   ei      = (const int*)d_in[1];
    const float* W_embed = (const float*)d_in[2];
    const float* b_embed = (const float*)d_in[3];
    const float* W1      = (const float*)d_in[4];
    const float* b1      = (const float*)d_in[5];
    const float* W2      = (const float*)d_in[6];
    const float* b2      = (const float*)d_in[7];
    float* out = (float*)d_out;

    int N = in_sizes[0] / 118;
    int E = in_sizes[1] / 2;
    int SB = (N + 1023) / 1024;
    int Mpad = ((N + 127) / 128) * 128;         // 20096
    size_t NC = (size_t)Mpad * CH;

    // workspace layout; tpk (u32 [Mpad][256]) occupies the th+tl region
    _Float16* hh   = (_Float16*)d_ws;           // tiled [8][Mpad][32]
    _Float16* hl   = hh + NC;
    _Float16* th   = hl + NC;                   // tpk region (2*NC halves)
    _Float16* tl   = th + NC;
    _Float16* ah   = tl + NC;                   // tiled
    _Float16* al   = ah + NC;
    _Float16* WThi = al + NC;                   // tiled [8 mats][8][256][32]
    _Float16* WTlo = WThi + 8 * 65536;
    _Float16* WeTh = WTlo + 8 * 65536;          // tiled [4][256][32]
    _Float16* WeTl = WeTh + 32768;
    float*    inv      = (float*)(WeTl + 32768);
    int*      deg      = (int*)(inv + N);
    int*      row_ptr  = deg + N;
    int*      fill_pos = row_ptr + (N + 1);
    int*      colv     = fill_pos + N;
    int*      bsum     = colv + E;
    int*      boff     = bsum + 256;

    uint32_t* tpk = (uint32_t*)th;              // packed t: [Mpad][256] u32
    _Float16* xh = th;                          // tiled [4][Mpad][32] (pre-embed)
    _Float16* xl = th + (size_t)Mpad * 128;

    // CSR build + weight/input splits (deterministic, per launch)
    zero_int_kernel<<<(N + 255) / 256, 256, 0, stream>>>(deg, N);
    degree_kernel<<<(E + 255) / 256, 256, 0, stream>>>(ei, E, deg);
    scan_part_kernel<<<SB, 256, 0, stream>>>(deg, bsum, N);
    scan_top_kernel<<<1, 256, 0, stream>>>(bsum, boff, SB);
    scan_final_kernel<<<SB, 256, 0, stream>>>(deg, boff, row_ptr, fill_pos, inv, N, E);
    fill_kernel<<<(E + 255) / 256, 256, 0, stream>>>(ei, E, fill_pos, colv);
    wsplit_kernel<<<256, 256, 0, stream>>>(W1, W2, WThi, WTlo);
    wesplit_kernel<<<16, 256, 0, stream>>>(W_embed, WeTh, WeTl);
    xsplit_kernel<<<(N * 16 + 255) / 256, 256, 0, stream>>>(x, xh, xl, N, Mpad);

    int mtiles = Mpad / 128;                    // 157
    int MC = (mtiles + 7) / 8;                  // 20
    int mgrid = 8 * MC * 4;                     // 640 blocks
    int agrid = 8 * ((N + 15) / 16);            // 8 slices x 1250 node-groups

    // embed: h = x @ W_embed + b_embed (tiled out), K=128 -> KT=4
    mgemm_kernel<4, false, true><<<mgrid, 256, 0, stream>>>(xh, xl, WeTh, WeTl, b_embed,
                                                            hh, hl, Mpad, MC);
    for (int l = 0; l < 4; l++) {
        // t = gelu(h@W1+b1): PACKED u32 out (consumed by slice-agg)
        mgemm_kernel<8, true, false><<<mgrid, 256, 0, stream>>>(hh, hl,
                                                                WThi + (size_t)l * 65536,
                                                                WTlo + (size_t)l * 65536,
                                                                b1 + (size_t)l * CH,
                                                                (_Float16*)tpk, nullptr,
                                                                Mpad, MC);
        agg_kernel<<<agrid, 256, 0, stream>>>(tpk, row_ptr, colv, inv, ah, al, N, Mpad);
        // h = gelu(agg@W2+b2): tiled out
        mgemm_kernel<8, true, true><<<mgrid, 256, 0, stream>>>(ah, al,
                                                               WThi + (size_t)(4 + l) * 65536,
                                                               WTlo + (size_t)(4 + l) * 65536,
                                                               b2 + (size_t)l * CH,
                                                               hh, hl, Mpad, MC);
    }
    mean_kernel<<<(N + 3) / 4, 256, 0, stream>>>(hh, hl, out, N, Mpad);
}

// Round 17
// 399.428 us; speedup vs baseline: 1.4375x; 1.4375x over previous
//
#include <hip/hip_runtime.h>
#include <math.h>
#include <stdint.h>

#define CH 256

typedef _Float16 half8 __attribute__((ext_vector_type(8)));
typedef _Float16 half4 __attribute__((ext_vector_type(4)));
typedef _Float16 half2v __attribute__((ext_vector_type(2)));
typedef float f32x4 __attribute__((ext_vector_type(4)));

__device__ __forceinline__ float gelu_exact(float v) {
    return 0.5f * v * (1.0f + erff(v * 0.70710678118654752f));
}

// acc += hi + lo of a packed (hi,lo) u32, one VALU op via v_dot2_f32_f16
__device__ __forceinline__ float acc_pk(uint32_t u, float acc) {
    half2v h = __builtin_bit_cast(half2v, u);
#if __has_builtin(__builtin_amdgcn_fdot2)
    half2v ones = {(_Float16)1.0f, (_Float16)1.0f};
    return __builtin_amdgcn_fdot2(h, ones, acc, false);
#else
    return acc + (float)h.x + (float)h.y;
#endif
}

// ---- W1/W2 pre-split into k-tiled transposed layout: WT[mat][kt][n][32] ----
__global__ void wsplit_kernel(const float* __restrict__ W1, const float* __restrict__ W2,
                              _Float16* __restrict__ WThi, _Float16* __restrict__ WTlo) {
    int idx = blockIdx.x * blockDim.x + threadIdx.x;  // 65536 threads
    int n   = idx & 255;
    int kg  = (idx >> 8) & 31;     // k-group of 8
    int mat = idx >> 13;
    const float* W = (mat < 4) ? (W1 + (size_t)mat * 65536)
                               : (W2 + (size_t)(mat - 4) * 65536);
    _Float16 hi[8], lo[8];
#pragma unroll
    for (int j = 0; j < 8; j++) {
        float v = W[(size_t)(kg * 8 + j) * CH + n];
        _Float16 h = (_Float16)v;
        hi[j] = h;
        lo[j] = (_Float16)(v - (float)h);
    }
    size_t off = (size_t)mat * 65536 + ((size_t)(kg >> 2) * 256 + n) * 32 + (kg & 3) * 8;
    *(half8*)(WThi + off) = *(half8*)&hi[0];
    *(half8*)(WTlo + off) = *(half8*)&lo[0];
}

// ---- W_embed pre-split tiled: [4][256][32] (K padded 118 -> 128) ----
__global__ void wesplit_kernel(const float* __restrict__ We,
                               _Float16* __restrict__ WeTh, _Float16* __restrict__ WeTl) {
    int idx = blockIdx.x * blockDim.x + threadIdx.x;  // 4096 threads
    if (idx >= 4096) return;
    int n  = idx >> 4;
    int k8 = (idx & 15) * 8;
    _Float16 hi[8], lo[8];
#pragma unroll
    for (int j = 0; j < 8; j++) {
        int k = k8 + j;
        float v = (k < 118) ? We[(size_t)k * CH + n] : 0.f;
        _Float16 h = (_Float16)v;
        hi[j] = h;
        lo[j] = (_Float16)(v - (float)h);
    }
    size_t off = ((size_t)(k8 >> 5) * 256 + n) * 32 + (k8 & 31);
    *(half8*)(WeTh + off) = *(half8*)&hi[0];
    *(half8*)(WeTl + off) = *(half8*)&lo[0];
}

// ---- x pre-split tiled: [4][Mpad][32] ----
__global__ void xsplit_kernel(const float* __restrict__ x,
                              _Float16* __restrict__ xh, _Float16* __restrict__ xl,
                              int N, int Mpad) {
    int idx = blockIdx.x * blockDim.x + threadIdx.x;
    int n  = idx >> 4;
    int c8 = (idx & 15) * 8;
    if (n >= N) return;
    _Float16 hi[8], lo[8];
#pragma unroll
    for (int j = 0; j < 8; j++) {
        int c = c8 + j;
        float v = (c < 118) ? x[(size_t)n * 118 + c] : 0.f;
        _Float16 h = (_Float16)v;
        hi[j] = h;
        lo[j] = (_Float16)(v - (float)h);
    }
    size_t off = ((size_t)(c8 >> 5) * Mpad + n) * 32 + (c8 & 31);
    *(half8*)(xh + off) = *(half8*)&hi[0];
    *(half8*)(xl + off) = *(half8*)&lo[0];
}

// ---- fp16-split 3-pass MFMA GEMM (R11/R14 proven structure: BK=32) ----
// OUTMODE 0: tiled split hi/lo pair (Oh, Ol). OUTMODE 1: packed u32 [Mpad][256]
// into Oh. OUTMODE 2: fused row-mean partials (f32) into Oh-cast buffer [8][Mpad].
template<int KT, bool DOGELU, int OUTMODE>
__global__ __launch_bounds__(256, 4) void mgemm_kernel(
    const _Float16* __restrict__ Ah_g, const _Float16* __restrict__ Al_g,
    const _Float16* __restrict__ Bh_g, const _Float16* __restrict__ Bl_g,
    const float* __restrict__ bias,
    _Float16* __restrict__ Oh, _Float16* __restrict__ Ol,
    int Mpad, int MC)
{
    __shared__ __align__(16) char smem[30720];
    _Float16 (*Ah)[40] = (_Float16(*)[40])smem;             // 128x40x2B = 10240
    _Float16 (*Al)[40] = (_Float16(*)[40])(smem + 10240);
    _Float16 (*Bh)[40] = (_Float16(*)[40])(smem + 20480);   // 64x40x2B = 5120
    _Float16 (*Bl)[40] = (_Float16(*)[40])(smem + 25600);
    uint32_t (*Obuf)[68] = (uint32_t(*)[68])smem;           // 64x68x4B = 17408 (reused)

    int b    = blockIdx.x;
    int xcd  = b & 7;
    int slot = b >> 3;
    int mt   = xcd * MC + (slot >> 2);
    int nt   = slot & 3;
    if (mt * 128 >= Mpad) return;
    int m0 = mt * 128;
    int n0 = nt * 64;

    int tid  = threadIdx.x;
    int lane = tid & 63;
    int wave = tid >> 6;
    int wr = wave >> 1;
    int wc = wave & 1;

    f32x4 acc[4][2];
#pragma unroll
    for (int i = 0; i < 4; i++)
#pragma unroll
        for (int j = 0; j < 2; j++) acc[i][j] = (f32x4){0.f, 0.f, 0.f, 0.f};

    const int Lb    = tid * 8;        // half index within a 4KB chunk
    const int arow0 = Lb >> 5;        // 0..63
    const int ak    = Lb & 31;        // 0,8,16,24

    for (int kt = 0; kt < KT; kt++) {
        const _Float16* pah = Ah_g + ((size_t)kt * Mpad + m0) * 32;
        const _Float16* pal = Al_g + ((size_t)kt * Mpad + m0) * 32;
        const _Float16* pbh = Bh_g + ((size_t)kt * 256 + n0) * 32;
        const _Float16* pbl = Bl_g + ((size_t)kt * 256 + n0) * 32;
        half8 a0 = *(const half8*)(pah + Lb);
        half8 a1 = *(const half8*)(pah + 2048 + Lb);
        half8 a2 = *(const half8*)(pal + Lb);
        half8 a3 = *(const half8*)(pal + 2048 + Lb);
        half8 b0 = *(const half8*)(pbh + Lb);
        half8 b1 = *(const half8*)(pbl + Lb);
        *(half8*)&Ah[arow0][ak]      = a0;
        *(half8*)&Ah[64 + arow0][ak] = a1;
        *(half8*)&Al[arow0][ak]      = a2;
        *(half8*)&Al[64 + arow0][ak] = a3;
        *(half8*)&Bh[arow0][ak]      = b0;
        *(half8*)&Bl[arow0][ak]      = b1;
        __syncthreads();

        {
            int frow = lane & 15;
            int fk   = (lane >> 4) * 8;
            half8 ah[4], al[4], bh[2], bl[2];
#pragma unroll
            for (int rf = 0; rf < 4; rf++) {
                int r = wr * 64 + rf * 16 + frow;
                ah[rf] = *(const half8*)&Ah[r][fk];
                al[rf] = *(const half8*)&Al[r][fk];
            }
#pragma unroll
            for (int cf = 0; cf < 2; cf++) {
                int c = wc * 32 + cf * 16 + frow;
                bh[cf] = *(const half8*)&Bh[c][fk];
                bl[cf] = *(const half8*)&Bl[c][fk];
            }
#pragma unroll
            for (int rf = 0; rf < 4; rf++)
#pragma unroll
                for (int cf = 0; cf < 2; cf++) {
                    acc[rf][cf] = __builtin_amdgcn_mfma_f32_16x16x32_f16(ah[rf], bh[cf], acc[rf][cf], 0, 0, 0);
                    acc[rf][cf] = __builtin_amdgcn_mfma_f32_16x16x32_f16(ah[rf], bl[cf], acc[rf][cf], 0, 0, 0);
                    acc[rf][cf] = __builtin_amdgcn_mfma_f32_16x16x32_f16(al[rf], bh[cf], acc[rf][cf], 0, 0, 0);
                }
        }
        __syncthreads();
    }

    int ccol = lane & 15;
    int crow = (lane >> 4) * 4;
    float bb[2];
    bb[0] = bias[n0 + wc * 32 + ccol];
    bb[1] = bias[n0 + wc * 32 + 16 + ccol];

    if (OUTMODE == 2) {
        // ---- fused row-mean: wave reduces its 32-col slice per row, writes
        // one f32 partial per (row, nt*2+wc) to partial[8][Mpad]. Deterministic.
        float* partial = (float*)Oh;
#pragma unroll
        for (int rf = 0; rf < 4; rf++) {
#pragma unroll
            for (int q = 0; q < 4; q++) {
                float v0 = acc[rf][0][q] + bb[0];
                float v1 = acc[rf][1][q] + bb[1];
                float s = (DOGELU ? gelu_exact(v0) : v0) + (DOGELU ? gelu_exact(v1) : v1);
                s += __shfl_xor(s, 1, 64);
                s += __shfl_xor(s, 2, 64);
                s += __shfl_xor(s, 4, 64);
                s += __shfl_xor(s, 8, 64);
                if (ccol == 0) {
                    int grow = m0 + wr * 64 + rf * 16 + crow + q;
                    partial[(size_t)(nt * 2 + wc) * Mpad + grow] = s;
                }
            }
        }
        return;
    }

    // ---- epilogue: pack hi/lo u32 -> LDS -> coalesced stores ----
#pragma unroll
    for (int half = 0; half < 2; half++) {
        if (wr == half) {
#pragma unroll
            for (int cf = 0; cf < 2; cf++)
#pragma unroll
                for (int rf = 0; rf < 4; rf++)
#pragma unroll
                    for (int q = 0; q < 4; q++) {
                        float v = acc[rf][cf][q] + bb[cf];
                        float g = DOGELU ? gelu_exact(v) : v;
                        _Float16 hi = (_Float16)g;
                        _Float16 lo = (_Float16)(g - (float)hi);
                        uint32_t u = (uint32_t)__builtin_bit_cast(uint16_t, hi)
                                   | ((uint32_t)__builtin_bit_cast(uint16_t, lo) << 16);
                        Obuf[rf * 16 + crow + q][wc * 32 + cf * 16 + ccol] = u;
                    }
        }
        __syncthreads();
#pragma unroll
        for (int i = 0; i < 8; i++) {
            int idx = i * 512 + tid * 2;
            int row = idx >> 6;
            int c   = idx & 63;
            uint32_t u0 = Obuf[row][c];
            uint32_t u1 = Obuf[row][c + 1];
            int grow = m0 + half * 64 + row;
            int gcol = n0 + c;
            if (OUTMODE == 0) {
                uint32_t hi2 = (u0 & 0xffffu) | (u1 << 16);
                uint32_t lo2 = (u0 >> 16) | (u1 & 0xffff0000u);
                size_t off = ((size_t)(gcol >> 5) * Mpad + grow) * 32 + (gcol & 31);
                *(uint32_t*)(Oh + off) = hi2;
                *(uint32_t*)(Ol + off) = lo2;
            } else {
                uint2 pk; pk.x = u0; pk.y = u1;
                *(uint2*)((uint32_t*)Oh + (size_t)grow * CH + gcol) = pk;
            }
        }
        __syncthreads();
    }
}

// ---------------- CSR build ----------------
__global__ void degree_kernel(const int* __restrict__ ei, int E, int* deg) {
    int e = blockIdx.x * blockDim.x + threadIdx.x;
    if (e < E) atomicAdd(&deg[ei[E + e]], 1);
}

__global__ void scan_part_kernel(const int* __restrict__ deg, int* bsum, int N) {
    int t = threadIdx.x;
    int base = blockIdx.x * 1024 + t * 4;
    int4 v = {0, 0, 0, 0};
    if (base + 3 < N) v = *(const int4*)(deg + base);
    else {
        if (base + 0 < N) v.x = deg[base + 0];
        if (base + 1 < N) v.y = deg[base + 1];
        if (base + 2 < N) v.z = deg[base + 2];
        if (base + 3 < N) v.w = deg[base + 3];
    }
    __shared__ int sh[256];
    sh[t] = v.x + v.y + v.z + v.w;
    __syncthreads();
    for (int off = 128; off; off >>= 1) {
        if (t < off) sh[t] += sh[t + off];
        __syncthreads();
    }
    if (t == 0) bsum[blockIdx.x] = sh[0];
}

__global__ void scan_top_kernel(const int* __restrict__ bsum, int* boff, int B) {
    __shared__ int sh[256];
    int t = threadIdx.x;
    int own = (t < B) ? bsum[t] : 0;
    sh[t] = own;
    __syncthreads();
    for (int off = 1; off < 256; off <<= 1) {
        int v = (t >= off) ? sh[t - off] : 0;
        __syncthreads();
        sh[t] += v;
        __syncthreads();
    }
    if (t < B) boff[t] = sh[t] - own;
}

__global__ void scan_final_kernel(const int* __restrict__ deg, const int* __restrict__ boff,
                                  int* row_ptr, int* fill_pos, float* inv, int N, int E) {
    int t = threadIdx.x;
    int base = blockIdx.x * 1024 + t * 4;
    int4 v = {0, 0, 0, 0};
    if (base + 3 < N) v = *(const int4*)(deg + base);
    else {
        if (base + 0 < N) v.x = deg[base + 0];
        if (base + 1 < N) v.y = deg[base + 1];
        if (base + 2 < N) v.z = deg[base + 2];
        if (base + 3 < N) v.w = deg[base + 3];
    }
    int own = v.x + v.y + v.z + v.w;
    __shared__ int sh[256];
    sh[t] = own;
    __syncthreads();
    for (int off = 1; off < 256; off <<= 1) {
        int s = (t >= off) ? sh[t - off] : 0;
        __syncthreads();
        sh[t] += s;
        __syncthreads();
    }
    int run = boff[blockIdx.x] + (sh[t] - own);
    int4 rp;
    rp.x = run;
    rp.y = run + v.x;
    rp.z = rp.y + v.y;
    rp.w = rp.z + v.z;
    if (base + 3 < N) {
        *(int4*)(row_ptr + base) = rp;
        *(int4*)(fill_pos + base) = rp;
        float4 iv;
        iv.x = 1.0f / fmaxf((float)v.x, 1.0f);
        iv.y = 1.0f / fmaxf((float)v.y, 1.0f);
        iv.z = 1.0f / fmaxf((float)v.z, 1.0f);
        iv.w = 1.0f / fmaxf((float)v.w, 1.0f);
        *(float4*)(inv + base) = iv;
    } else {
        int rr[4] = {rp.x, rp.y, rp.z, rp.w};
        int dd[4] = {v.x, v.y, v.z, v.w};
        for (int q = 0; q < 4; q++) {
            if (base + q < N) {
                row_ptr[base + q] = rr[q];
                fill_pos[base + q] = rr[q];
                inv[base + q] = 1.0f / fmaxf((float)dd[q], 1.0f);
            }
        }
    }
    if (blockIdx.x == 0 && t == 0) row_ptr[N] = E;
}

__global__ void fill_kernel(const int* __restrict__ ei, int E, int* fill_pos, int* colv) {
    int e = blockIdx.x * blockDim.x + threadIdx.x;
    if (e < E) {
        int p = atomicAdd(&fill_pos[ei[E + e]], 1);
        colv[p] = ei[e];
    }
}

// ---- aggregation (R14, best): XCD slice + uint2 loads + fdot2, 16 lanes/node ----
__global__ __launch_bounds__(256) void agg_kernel(
    const uint32_t* __restrict__ tpk,
    const int* __restrict__ row_ptr, const int* __restrict__ colv,
    const float* __restrict__ inv,
    _Float16* __restrict__ aggh, _Float16* __restrict__ aggl,
    int N, int Mpad)
{
    int b = blockIdx.x;
    int slice = b & 7;                          // 32-channel slice, pinned to XCD
    int n = (b >> 3) * 16 + (threadIdx.x >> 4); // one node per 16-lane group
    if (n >= N) return;
    int lane = threadIdx.x & 15;
    const uint32_t* base = tpk + slice * 32 + lane * 2;

    int s = row_ptr[n], e = row_ptr[n + 1];
    float e0 = 0.f, o0 = 0.f, e1 = 0.f, o1 = 0.f;   // 2 accum pairs (even/odd ch)
    int j = s;
    for (; j + 4 <= e; j += 4) {
        int c0 = colv[j], c1 = colv[j + 1], c2 = colv[j + 2], c3 = colv[j + 3];
        uint2 u0 = *(const uint2*)(base + (size_t)c0 * CH);
        uint2 u1 = *(const uint2*)(base + (size_t)c1 * CH);
        uint2 u2 = *(const uint2*)(base + (size_t)c2 * CH);
        uint2 u3 = *(const uint2*)(base + (size_t)c3 * CH);
        e0 = acc_pk(u0.x, e0); o0 = acc_pk(u0.y, o0);
        e1 = acc_pk(u1.x, e1); o1 = acc_pk(u1.y, o1);
        e0 = acc_pk(u2.x, e0); o0 = acc_pk(u2.y, o0);
        e1 = acc_pk(u3.x, e1); o1 = acc_pk(u3.y, o1);
    }
    for (; j < e; j++) {
        uint2 u = *(const uint2*)(base + (size_t)colv[j] * CH);
        e0 = acc_pk(u.x, e0); o0 = acc_pk(u.y, o0);
    }
    float sc = inv[n];
    float v0 = (e0 + e1) * sc;
    float v1 = (o0 + o1) * sc;
    _Float16 h0 = (_Float16)v0, h1 = (_Float16)v1;
    half2v oh = {h0, h1};
    half2v ol = {(_Float16)(v0 - (float)h0), (_Float16)(v1 - (float)h1)};
    size_t ooff = ((size_t)slice * Mpad + n) * 32 + lane * 2;  // tiled [kt][Mpad][32]
    *(half2v*)(aggh + ooff) = oh;
    *(half2v*)(aggl + ooff) = ol;
}

// ---- final mean: out[n] = (sum of 8 partials) / 256 ----
__global__ void finalmean_kernel(const float* __restrict__ partial,
                                 float* __restrict__ out, int N, int Mpad) {
    int n = blockIdx.x * 256 + threadIdx.x;
    if (n >= N) return;
    float s = 0.f;
#pragma unroll
    for (int p = 0; p < 8; p++) s += partial[(size_t)p * Mpad + n];
    out[n] = s * (1.0f / 256.0f);
}

extern "C" void kernel_launch(void* const* d_in, const int* in_sizes, int n_in,
                              void* d_out, int out_size, void* d_ws, size_t ws_size,
                              hipStream_t stream) {
    const float* x       = (const float*)d_in[0];
    const int*   ei      = (const int*)d_in[1];
    const float* W_embed = (const float*)d_in[2];
    const float* b_embed = (const float*)d_in[3];
    const float* W1      = (const float*)d_in[4];
    const float* b1      = (const float*)d_in[5];
    const float* W2      = (const float*)d_in[6];
    const float* b2      = (const float*)d_in[7];
    float* out = (float*)d_out;

    int N = in_sizes[0] / 118;
    int E = in_sizes[1] / 2;
    int SB = (N + 1023) / 1024;
    int Mpad = ((N + 127) / 128) * 128;         // 20096
    size_t NC = (size_t)Mpad * CH;

    // workspace layout; tpk (u32 [Mpad][256]) occupies the th+tl region
    _Float16* hh   = (_Float16*)d_ws;           // tiled [8][Mpad][32]
    _Float16* hl   = hh + NC;
    _Float16* th   = hl + NC;                   // tpk region (2*NC halves)
    _Float16* tl   = th + NC;
    _Float16* ah   = tl + NC;                   // tiled
    _Float16* al   = ah + NC;
    _Float16* WThi = al + NC;                   // tiled [8 mats][8][256][32]
    _Float16* WTlo = WThi + 8 * 65536;
    _Float16* WeTh = WTlo + 8 * 65536;          // tiled [4][256][32]
    _Float16* WeTl = WeTh + 32768;
    float*    inv      = (float*)(WeTl + 32768);
    int*      deg      = (int*)(inv + N);
    int*      row_ptr  = deg + N;
    int*      fill_pos = row_ptr + (N + 1);
    int*      colv     = fill_pos + N;
    int*      bsum     = colv + E;
    int*      boff     = bsum + 256;

    uint32_t* tpk = (uint32_t*)th;              // packed t: [Mpad][256] u32
    float*    partial = (float*)th;             // [8][Mpad] f32 (reuses tpk region)
    _Float16* xh = th;                          // tiled [4][Mpad][32] (pre-embed)
    _Float16* xl = th + (size_t)Mpad * 128;

    // CSR build + weight/input splits (deterministic, per launch)
    hipMemsetAsync(deg, 0, (size_t)N * sizeof(int), stream);
    degree_kernel<<<(E + 255) / 256, 256, 0, stream>>>(ei, E, deg);
    scan_part_kernel<<<SB, 256, 0, stream>>>(deg, bsum, N);
    scan_top_kernel<<<1, 256, 0, stream>>>(bsum, boff, SB);
    scan_final_kernel<<<SB, 256, 0, stream>>>(deg, boff, row_ptr, fill_pos, inv, N, E);
    fill_kernel<<<(E + 255) / 256, 256, 0, stream>>>(ei, E, fill_pos, colv);
    wsplit_kernel<<<256, 256, 0, stream>>>(W1, W2, WThi, WTlo);
    wesplit_kernel<<<16, 256, 0, stream>>>(W_embed, WeTh, WeTl);
    xsplit_kernel<<<(N * 16 + 255) / 256, 256, 0, stream>>>(x, xh, xl, N, Mpad);

    int mtiles = Mpad / 128;                    // 157
    int MC = (mtiles + 7) / 8;                  // 20
    int mgrid = 8 * MC * 4;                     // 640 blocks
    int agrid = 8 * ((N + 15) / 16);            // 8 slices x 1250 node-groups

    // embed: h = x @ W_embed + b_embed (tiled out), K=128 -> KT=4
    mgemm_kernel<4, false, 0><<<mgrid, 256, 0, stream>>>(xh, xl, WeTh, WeTl, b_embed,
                                                         hh, hl, Mpad, MC);
    for (int l = 0; l < 4; l++) {
        // t = gelu(h@W1+b1): PACKED u32 out (consumed by slice-agg)
        mgemm_kernel<8, true, 1><<<mgrid, 256, 0, stream>>>(hh, hl,
                                                            WThi + (size_t)l * 65536,
                                                            WTlo + (size_t)l * 65536,
                                                            b1 + (size_t)l * CH,
                                                            (_Float16*)tpk, nullptr,
                                                            Mpad, MC);
        agg_kernel<<<agrid, 256, 0, stream>>>(tpk, row_ptr, colv, inv, ah, al, N, Mpad);
        if (l < 3) {
            // h = gelu(agg@W2+b2): tiled out
            mgemm_kernel<8, true, 0><<<mgrid, 256, 0, stream>>>(ah, al,
                                                                WThi + (size_t)(4 + l) * 65536,
                                                                WTlo + (size_t)(4 + l) * 65536,
                                                                b2 + (size_t)l * CH,
                                                                hh, hl, Mpad, MC);
        } else {
            // final layer: fused row-mean partials (no h materialization)
            mgemm_kernel<8, true, 2><<<mgrid, 256, 0, stream>>>(ah, al,
                                                                WThi + (size_t)(4 + l) * 65536,
                                                                WTlo + (size_t)(4 + l) * 65536,
                                                                b2 + (size_t)l * CH,
                                                                (_Float16*)partial, nullptr,
                                                                Mpad, MC);
        }
    }
    finalmean_kernel<<<(N + 255) / 256, 256, 0, stream>>>(partial, out, N, Mpad);
}